// Round 9
// baseline (248.093 us; speedup 1.0000x reference)
//
#include <hip/hip_runtime.h>

// ---------------------------------------------------------------------------
// SupervisedGATEncoder: 2-layer GAT (4 heads x 64 -> BN -> ReLU -> 1 head x 32)
// + graph-mean prediction head.
//
// R15: agg0 barrier-free. R14's block-wide __syncthreads + wave0-only MFMA
// tail cost ~14% occupancy (53% vs 67% unfused; BW tracks occupancy). Now
// each wave computes its OWN node's h1 row: row staged in a 512B wave-
// private LDS slab, MFMA A-operand reads it as a broadcast (all 16 fragment
// rows = same row; identical numerics), 16 MFMAs/wave, no barrier, waves
// retire independently. LDS 9216 -> 3072 B.
// Rest as R14 (merged hist+swizzle, relaxed-atomic gsum in agg1 + 1-block
// pred, fused gemm1, agg1 dedup, exp2/log2e folding, merged scans).
// ---------------------------------------------------------------------------

#define NEG_SLOPE 0.2f
#define BN_EPS 1e-5f
#define LOG2E 1.4426950408889634f

typedef __attribute__((ext_vector_type(8))) short bf16x8;
typedef __attribute__((ext_vector_type(4))) float f32x4;

__device__ __forceinline__ float bf2f(unsigned short u) {
  return __uint_as_float((unsigned)u << 16);
}
__device__ __forceinline__ unsigned short f2bf(float f) {
  unsigned u = __float_as_uint(f);
  u += 0x7fff + ((u >> 16) & 1);   // round-to-nearest-even
  return (unsigned short)(u >> 16);
}

// -------- CSR histogram + (merged) W0/W1 bf16 swizzle ----------------------
__global__ __launch_bounds__(256) void hist_swz_kernel(
    const int* __restrict__ dsts, int* __restrict__ deg, int E, int N,
    int histBlocks, const float* __restrict__ W0, const float* __restrict__ W1,
    unsigned short* __restrict__ w0sw, unsigned short* __restrict__ w1sw) {
  const int b = blockIdx.x;
  if (b < histBlocks) {
    int e = b * 256 + threadIdx.x;
    if (e >= E + N) return;
    int d = (e < E) ? dsts[e] : e - E;
    atomicAdd(&deg[d], 1);
  } else {
    int o = (b - histBlocks) * 256 + threadIdx.x;
    if (o < 32768) {
      int j = o & 7, l = (o >> 3) & 63, ks = (o >> 9) & 3,
          ci = (o >> 11) & 3, h = (o >> 13) & 3;
      int row = ks * 32 + (l >> 4) * 8 + j;
      int col = h * 64 + ci * 16 + (l & 15);
      w0sw[o] = f2bf(W0[row * 256 + col]);
    } else if (o < 40960) {
      int o2 = o - 32768;
      int j = o2 & 7, l = (o2 >> 3) & 63, ks = (o2 >> 9) & 7, ci = (o2 >> 12) & 1;
      int row = ks * 32 + (l >> 4) * 8 + j;
      int col = ci * 16 + (l & 15);
      w1sw[o2] = f2bf(W1[row * 32 + col]);
    }
  }
}

// ---------------- GEMM0 (MFMA): h0[M,256] = x[M,128] @ W0[128,256] ---------
__global__ __launch_bounds__(256) void gemm0_mfma_kernel(
    const float* __restrict__ x, const unsigned short* __restrict__ w0sw,
    const float* __restrict__ a_src0, const float* __restrict__ a_dst0,
    unsigned short* __restrict__ h0bf, float* __restrict__ as0,
    float* __restrict__ ad0, int M) {
  __shared__ unsigned short Asw[16 * 64 * 8];   // 16 KB
  const int t = threadIdx.x;
  const int lane = t & 63;
  const int h = t >> 6;            // wave id == head
  const int row0 = blockIdx.x * 64;

  #pragma unroll
  for (int i = 0; i < 8; ++i) {
    int q = t + 256 * i;
    int r = q >> 5, c4 = q & 31;
    int gr = row0 + r;
    float4 v = make_float4(0.f, 0.f, 0.f, 0.f);
    if (gr < M) v = *reinterpret_cast<const float4*>(&x[(size_t)gr * 128 + c4 * 4]);
    int ks = c4 >> 3;
    int lane_hi = (c4 >> 1) & 3;
    int j0 = (c4 & 1) * 4;
    int slot = (r >> 4) * 4 + ks;
    int dlane = (r & 15) + 16 * lane_hi;
    ushort4 o;
    o.x = f2bf(v.x); o.y = f2bf(v.y); o.z = f2bf(v.z); o.w = f2bf(v.w);
    *reinterpret_cast<ushort4*>(&Asw[(slot * 64 + dlane) * 8 + j0]) = o;
  }
  __syncthreads();

  f32x4 acc[4][4] = {};
  const bf16x8* wp = reinterpret_cast<const bf16x8*>(w0sw);
  #pragma unroll
  for (int ks = 0; ks < 4; ++ks) {
    bf16x8 bfrag[4];
    #pragma unroll
    for (int ci = 0; ci < 4; ++ci)
      bfrag[ci] = wp[(h * 16 + ci * 4 + ks) * 64 + lane];
    #pragma unroll
    for (int ri = 0; ri < 4; ++ri) {
      bf16x8 af = *reinterpret_cast<const bf16x8*>(&Asw[((ri * 4 + ks) * 64 + lane) * 8]);
      #pragma unroll
      for (int ci = 0; ci < 4; ++ci)
        acc[ri][ci] = __builtin_amdgcn_mfma_f32_16x16x32_bf16(af, bfrag[ci], acc[ri][ci], 0, 0, 0);
    }
  }

  float av[4], dv[4];
  #pragma unroll
  for (int ci = 0; ci < 4; ++ci) {
    av[ci] = a_src0[h * 64 + ci * 16 + (lane & 15)];
    dv[ci] = a_dst0[h * 64 + ci * 16 + (lane & 15)];
  }
  const int mrow = (lane >> 4) * 4;
  #pragma unroll
  for (int ri = 0; ri < 4; ++ri) {
    #pragma unroll
    for (int r = 0; r < 4; ++r) {
      int gr = row0 + ri * 16 + mrow + r;
      float ps = acc[ri][0][r] * av[0] + acc[ri][1][r] * av[1] +
                 acc[ri][2][r] * av[2] + acc[ri][3][r] * av[3];
      float pd = acc[ri][0][r] * dv[0] + acc[ri][1][r] * dv[1] +
                 acc[ri][2][r] * dv[2] + acc[ri][3][r] * dv[3];
      #pragma unroll
      for (int off = 1; off < 16; off <<= 1) {
        ps += __shfl_xor(ps, off);
        pd += __shfl_xor(pd, off);
      }
      if (gr < M) {
        #pragma unroll
        for (int ci = 0; ci < 4; ++ci)
          h0bf[(size_t)gr * 256 + h * 64 + ci * 16 + (lane & 15)] = f2bf(acc[ri][ci][r]);
        // pre-scale by log2(e): consumer uses exp2(max(x, .2x))
        if ((lane & 15) == 0) { as0[gr * 4 + h] = ps * LOG2E; ad0[gr * 4 + h] = pd * LOG2E; }
      }
    }
  }
}

// ------------------------- CSR scans + scatter -----------------------------
__global__ __launch_bounds__(256) void scan_block_kernel(
    const int* __restrict__ deg, int* __restrict__ excl,
    int* __restrict__ bsum, int N) {
  __shared__ int tmp[256];
  int i = blockIdx.x * 256 + threadIdx.x;
  int v = (i < N) ? deg[i] : 0;
  tmp[threadIdx.x] = v;
  __syncthreads();
  #pragma unroll
  for (int off = 1; off < 256; off <<= 1) {
    int t = (threadIdx.x >= off) ? tmp[threadIdx.x - off] : 0;
    __syncthreads();
    tmp[threadIdx.x] += t;
    __syncthreads();
  }
  if (i < N) excl[i] = tmp[threadIdx.x] - v;
  if (threadIdx.x == 255) bsum[blockIdx.x] = tmp[255];
}

// scan_add computes its own block prefix from bsum (NB <= 256).
__global__ __launch_bounds__(256) void scan_add_kernel(
    int* __restrict__ rowptr, const int* __restrict__ bsum,
    int* __restrict__ cursor, int N, int Etot) {
  __shared__ int wred[4];
  const int t = threadIdx.x;
  int v = (t < blockIdx.x) ? bsum[t] : 0;   // blockIdx.x <= NB-1 <= 255
  #pragma unroll
  for (int off = 32; off >= 1; off >>= 1) v += __shfl_xor(v, off);
  if ((t & 63) == 0) wred[t >> 6] = v;
  __syncthreads();
  const int prefix = wred[0] + wred[1] + wred[2] + wred[3];
  int i = blockIdx.x * 256 + t;
  if (i < N) {
    int r = rowptr[i] + prefix;
    rowptr[i] = r;
    cursor[i] = r;
  }
  if (i == 0) rowptr[N] = Etot;
}

__global__ __launch_bounds__(256) void scatter_kernel(
    const int* __restrict__ srcs, const int* __restrict__ dsts,
    int* __restrict__ cursor, int* __restrict__ csr_src, int E, int N) {
  int e = blockIdx.x * 256 + threadIdx.x;
  if (e >= E + N) return;
  int s, d;
  if (e < E) { s = srcs[e]; d = dsts[e]; } else { s = d = e - E; }
  int pos = atomicAdd(&cursor[d], 1);
  csr_src[pos] = s;
}

// ------ layer-0 aggregate (R11 loop, barrier-free) + per-wave gemm1 --------
// One wave per node. 16-edge groups: per-lane weight (zero-padded slab),
// always-full 8-wide gather batches (clamped srcs = L1-hit dups, zero
// weights exact). Tail: wave stages its BN+ReLU row in a 512B wave-private
// slab; MFMA A-operand reads it as a broadcast (all 16 rows identical ->
// same numerics), 16 MFMAs/wave, NO __syncthreads.
__global__ __launch_bounds__(256) void agg0_kernel(
    const int* __restrict__ rowptr, const int* __restrict__ csr_src,
    const unsigned short* __restrict__ h0bf, const float* __restrict__ as0,
    const float* __restrict__ ad0, const float* __restrict__ b0,
    const float* __restrict__ gamma, const float* __restrict__ beta,
    const float* __restrict__ mean, const float* __restrict__ var,
    const unsigned short* __restrict__ w1sw,
    const float* __restrict__ a_src1, const float* __restrict__ a_dst1,
    unsigned short* __restrict__ h1bf, float* __restrict__ as1,
    float* __restrict__ ad1, int N) {
  __shared__ float wlds[4][64];                // wave-private weight slab (1KB)
  __shared__ unsigned short rowsl[4][256];     // wave-private row slab (2KB)
  const int lane = threadIdx.x & 63;
  const int wid = threadIdx.x >> 6;
  const int n = blockIdx.x * 4 + wid;
  if (n >= N) return;                          // wave-uniform; no barrier below
  const int h = lane >> 4;
  const int eidx = lane & 15;
  const int bb = lane & 48;

  const int beg = rowptr[n], end = rowptr[n + 1];
  const float adv = ad0[n * 4 + h];
  float4 acc = make_float4(0.f, 0.f, 0.f, 0.f);
  float wsum = 0.f;

  for (int i = beg; i < end; i += 16) {
    const int rem = end - i;
    const int ne = rem < 16 ? rem : 16;
    const int li = (eidx < ne) ? eidx : (ne - 1);
    const int src = csr_src[i + li];
    float xx = as0[(unsigned)(src * 4 + h)] + adv;
    xx = fmaxf(xx, NEG_SLOPE * xx);
    float wl = (eidx < ne) ? exp2f(xx) : 0.f;
    wsum += wl;
    wlds[wid][lane] = wl;                      // same-wave write->read

    // batch 0: slots 0..7 (always; clamped srcs, zero-padded weights)
    {
      const int s0 = __builtin_amdgcn_readlane(src, 0);
      const int s1 = __builtin_amdgcn_readlane(src, 1);
      const int s2 = __builtin_amdgcn_readlane(src, 2);
      const int s3 = __builtin_amdgcn_readlane(src, 3);
      const int s4 = __builtin_amdgcn_readlane(src, 4);
      const int s5 = __builtin_amdgcn_readlane(src, 5);
      const int s6 = __builtin_amdgcn_readlane(src, 6);
      const int s7 = __builtin_amdgcn_readlane(src, 7);
      ushort4 v0 = *reinterpret_cast<const ushort4*>(&(h0bf + (size_t)s0 * 256)[lane * 4]);
      ushort4 v1 = *reinterpret_cast<const ushort4*>(&(h0bf + (size_t)s1 * 256)[lane * 4]);
      ushort4 v2 = *reinterpret_cast<const ushort4*>(&(h0bf + (size_t)s2 * 256)[lane * 4]);
      ushort4 v3 = *reinterpret_cast<const ushort4*>(&(h0bf + (size_t)s3 * 256)[lane * 4]);
      ushort4 v4 = *reinterpret_cast<const ushort4*>(&(h0bf + (size_t)s4 * 256)[lane * 4]);
      ushort4 v5 = *reinterpret_cast<const ushort4*>(&(h0bf + (size_t)s5 * 256)[lane * 4]);
      ushort4 v6 = *reinterpret_cast<const ushort4*>(&(h0bf + (size_t)s6 * 256)[lane * 4]);
      ushort4 v7 = *reinterpret_cast<const ushort4*>(&(h0bf + (size_t)s7 * 256)[lane * 4]);
      const float w0 = wlds[wid][bb + 0], w1 = wlds[wid][bb + 1];
      const float w2 = wlds[wid][bb + 2], w3 = wlds[wid][bb + 3];
      const float w4 = wlds[wid][bb + 4], w5 = wlds[wid][bb + 5];
      const float w6 = wlds[wid][bb + 6], w7 = wlds[wid][bb + 7];
      acc.x += ((w0 * bf2f(v0.x) + w1 * bf2f(v1.x)) + (w2 * bf2f(v2.x) + w3 * bf2f(v3.x))) +
               ((w4 * bf2f(v4.x) + w5 * bf2f(v5.x)) + (w6 * bf2f(v6.x) + w7 * bf2f(v7.x)));
      acc.y += ((w0 * bf2f(v0.y) + w1 * bf2f(v1.y)) + (w2 * bf2f(v2.y) + w3 * bf2f(v3.y))) +
               ((w4 * bf2f(v4.y) + w5 * bf2f(v5.y)) + (w6 * bf2f(v6.y) + w7 * bf2f(v7.y)));
      acc.z += ((w0 * bf2f(v0.z) + w1 * bf2f(v1.z)) + (w2 * bf2f(v2.z) + w3 * bf2f(v3.z))) +
               ((w4 * bf2f(v4.z) + w5 * bf2f(v5.z)) + (w6 * bf2f(v6.z) + w7 * bf2f(v7.z)));
      acc.w += ((w0 * bf2f(v0.w) + w1 * bf2f(v1.w)) + (w2 * bf2f(v2.w) + w3 * bf2f(v3.w))) +
               ((w4 * bf2f(v4.w) + w5 * bf2f(v5.w)) + (w6 * bf2f(v6.w) + w7 * bf2f(v7.w)));
    }
    // batch 1: slots 8..15 (wave-uniform skip when ne <= 8)
    if (ne > 8) {
      const int s0 = __builtin_amdgcn_readlane(src, 8);
      const int s1 = __builtin_amdgcn_readlane(src, 9);
      const int s2 = __builtin_amdgcn_readlane(src, 10);
      const int s3 = __builtin_amdgcn_readlane(src, 11);
      const int s4 = __builtin_amdgcn_readlane(src, 12);
      const int s5 = __builtin_amdgcn_readlane(src, 13);
      const int s6 = __builtin_amdgcn_readlane(src, 14);
      const int s7 = __builtin_amdgcn_readlane(src, 15);
      ushort4 v0 = *reinterpret_cast<const ushort4*>(&(h0bf + (size_t)s0 * 256)[lane * 4]);
      ushort4 v1 = *reinterpret_cast<const ushort4*>(&(h0bf + (size_t)s1 * 256)[lane * 4]);
      ushort4 v2 = *reinterpret_cast<const ushort4*>(&(h0bf + (size_t)s2 * 256)[lane * 4]);
      ushort4 v3 = *reinterpret_cast<const ushort4*>(&(h0bf + (size_t)s3 * 256)[lane * 4]);
      ushort4 v4 = *reinterpret_cast<const ushort4*>(&(h0bf + (size_t)s4 * 256)[lane * 4]);
      ushort4 v5 = *reinterpret_cast<const ushort4*>(&(h0bf + (size_t)s5 * 256)[lane * 4]);
      ushort4 v6 = *reinterpret_cast<const ushort4*>(&(h0bf + (size_t)s6 * 256)[lane * 4]);
      ushort4 v7 = *reinterpret_cast<const ushort4*>(&(h0bf + (size_t)s7 * 256)[lane * 4]);
      const float w0 = wlds[wid][bb + 8],  w1 = wlds[wid][bb + 9];
      const float w2 = wlds[wid][bb + 10], w3 = wlds[wid][bb + 11];
      const float w4 = wlds[wid][bb + 12], w5 = wlds[wid][bb + 13];
      const float w6 = wlds[wid][bb + 14], w7 = wlds[wid][bb + 15];
      acc.x += ((w0 * bf2f(v0.x) + w1 * bf2f(v1.x)) + (w2 * bf2f(v2.x) + w3 * bf2f(v3.x))) +
               ((w4 * bf2f(v4.x) + w5 * bf2f(v5.x)) + (w6 * bf2f(v6.x) + w7 * bf2f(v7.x)));
      acc.y += ((w0 * bf2f(v0.y) + w1 * bf2f(v1.y)) + (w2 * bf2f(v2.y) + w3 * bf2f(v3.y))) +
               ((w4 * bf2f(v4.y) + w5 * bf2f(v5.y)) + (w6 * bf2f(v6.y) + w7 * bf2f(v7.y)));
      acc.z += ((w0 * bf2f(v0.z) + w1 * bf2f(v1.z)) + (w2 * bf2f(v2.z) + w3 * bf2f(v3.z))) +
               ((w4 * bf2f(v4.z) + w5 * bf2f(v5.z)) + (w6 * bf2f(v6.z) + w7 * bf2f(v7.z)));
      acc.w += ((w0 * bf2f(v0.w) + w1 * bf2f(v1.w)) + (w2 * bf2f(v2.w) + w3 * bf2f(v3.w))) +
               ((w4 * bf2f(v4.w) + w5 * bf2f(v5.w)) + (w6 * bf2f(v6.w) + w7 * bf2f(v7.w)));
    }
  }

  // reduce wsum across the 16 lanes of this head group
  #pragma unroll
  for (int off = 1; off < 16; off <<= 1) wsum += __shfl_xor(wsum, off);

  const float inv = 1.0f / wsum;
  const int j = lane * 4;
  float4 bbv = *reinterpret_cast<const float4*>(&b0[j]);
  float4 mu = *reinterpret_cast<const float4*>(&mean[j]);
  float4 gg = *reinterpret_cast<const float4*>(&gamma[j]);
  float4 vv = *reinterpret_cast<const float4*>(&var[j]);
  float4 be = *reinterpret_cast<const float4*>(&beta[j]);
  float4 o;
  o.x = (acc.x * inv + bbv.x - mu.x) * (gg.x * rsqrtf(vv.x + BN_EPS)) + be.x;
  o.y = (acc.y * inv + bbv.y - mu.y) * (gg.y * rsqrtf(vv.y + BN_EPS)) + be.y;
  o.z = (acc.z * inv + bbv.z - mu.z) * (gg.z * rsqrtf(vv.z + BN_EPS)) + be.z;
  o.w = (acc.w * inv + bbv.w - mu.w) * (gg.w * rsqrtf(vv.w + BN_EPS)) + be.w;
  ushort4 ob;
  ob.x = f2bf(fmaxf(o.x, 0.f)); ob.y = f2bf(fmaxf(o.y, 0.f));
  ob.z = f2bf(fmaxf(o.z, 0.f)); ob.w = f2bf(fmaxf(o.w, 0.f));
  // stage the row (linear col order) into the wave-private slab
  *reinterpret_cast<ushort4*>(&rowsl[wid][lane * 4]) = ob;

  // ---- per-wave GEMM1 tail: h1[n,32] = row @ W1 via broadcast-A MFMA ----
  // A-frag read: lane needs cols [ks*32 + (lane>>4)*8, +8) -- identical for
  // all 16 lanes of a group (LDS broadcast). All 16 A-rows = our row.
  {
    const bf16x8* bp = reinterpret_cast<const bf16x8*>(w1sw);
    f32x4 c0 = {}, c1 = {};
    #pragma unroll
    for (int ks = 0; ks < 8; ++ks) {
      bf16x8 af = *reinterpret_cast<const bf16x8*>(&rowsl[wid][ks * 32 + (lane >> 4) * 8]);
      c0 = __builtin_amdgcn_mfma_f32_16x16x32_bf16(af, bp[(0 * 8 + ks) * 64 + lane], c0, 0, 0, 0);
      c1 = __builtin_amdgcn_mfma_f32_16x16x32_bf16(af, bp[(1 * 8 + ks) * 64 + lane], c1, 0, 0, 0);
    }
    // every C row equals the h1 row; use r=0, lanes 0-15 (col = lane&15)
    const float av0 = a_src1[lane & 15], av1 = a_src1[16 + (lane & 15)];
    const float dv0 = a_dst1[lane & 15], dv1 = a_dst1[16 + (lane & 15)];
    float ps = c0[0] * av0 + c1[0] * av1;
    float pd = c0[0] * dv0 + c1[0] * dv1;
    #pragma unroll
    for (int off = 1; off < 16; off <<= 1) {
      ps += __shfl_xor(ps, off);
      pd += __shfl_xor(pd, off);
    }
    if (lane < 16) {
      h1bf[(size_t)n * 32 + lane]      = f2bf(c0[0]);
      h1bf[(size_t)n * 32 + 16 + lane] = f2bf(c1[0]);
      if (lane == 0) { as1[n] = ps * LOG2E; ad1[n] = pd * LOG2E; }
    }
  }
}

// ------ layer-1 aggregate (dedup weights) + relaxed gsum accumulation ------
// Per-block: 4 nodes; after writing out rows, block reduces them into a
// 32-col partial and atomicAdds into one of 16 gsum replicas. No fence,
// no ticket: the following 1-block pred kernel provides ordering.
__global__ __launch_bounds__(256) void agg1_kernel(
    const int* __restrict__ rowptr, const int* __restrict__ csr_src,
    const unsigned short* __restrict__ h1bf, const float* __restrict__ as1,
    const float* __restrict__ ad1, const float* __restrict__ b1,
    float* __restrict__ out, float* __restrict__ gsum16, int N) {
  __shared__ float wslab[4][16];
  __shared__ int sslab[4][16];
  __shared__ float gred[4][32];
  const int t = threadIdx.x;
  const int lane = t & 63;
  const int wid = t >> 6;
  const int n = blockIdx.x * 4 + wid;
  const bool valid = n < N;
  const int c = lane & 31;
  const int half = lane >> 5;
  float val = 0.f;

  if (valid) {
    const int beg = rowptr[n], end = rowptr[n + 1];
    const float adv = ad1[n];
    float acc = 0.f, wsum = 0.f;

    for (int i = beg; i < end; i += 16) {
      int ne = end - i; if (ne > 16) ne = 16;
      if (lane < 16) {
        const int idx = lane < ne ? lane : ne - 1;
        const int s = csr_src[i + idx];
        const float x = as1[s] + adv;
        const float wl = (lane < ne) ? exp2f(fmaxf(x, NEG_SLOPE * x)) : 0.f;
        wslab[wid][lane] = wl;
        sslab[wid][lane] = s;
        wsum += wl;
      }
      for (int e = 0; e < ne; e += 8) {
        const int i0 = e + half, i1 = e + 2 + half, i2 = e + 4 + half, i3 = e + 6 + half;
        const int s0 = sslab[wid][i0], s1 = sslab[wid][i1],
                  s2 = sslab[wid][i2], s3 = sslab[wid][i3];
        const float w0 = wslab[wid][i0], w1 = wslab[wid][i1],
                    w2 = wslab[wid][i2], w3 = wslab[wid][i3];
        const unsigned short u0 = h1bf[(size_t)s0 * 32 + c];
        const unsigned short u1 = h1bf[(size_t)s1 * 32 + c];
        const unsigned short u2 = h1bf[(size_t)s2 * 32 + c];
        const unsigned short u3 = h1bf[(size_t)s3 * 32 + c];
        acc += (w0 * bf2f(u0) + w1 * bf2f(u1)) + (w2 * bf2f(u2) + w3 * bf2f(u3));
      }
    }
    // lanes 0-15 hold wsum partials; reduce within 16-group, then broadcast
    #pragma unroll
    for (int off = 1; off < 16; off <<= 1) wsum += __shfl_xor(wsum, off);
    wsum = __shfl(wsum, lane & 15);
    acc += __shfl_xor(acc, 32);
    if (half == 0) {
      val = acc / wsum + b1[c];
      out[(size_t)n * 32 + c] = val;
    }
  }

  // ---- block-level graph-sum partial (relaxed atomics, no fence) ----
  if (half == 0) gred[wid][c] = val;   // val==0 for invalid nodes
  __syncthreads();
  if (t < 32) {
    float v = gred[0][t] + gred[1][t] + gred[2][t] + gred[3][t];
    atomicAdd(&gsum16[(blockIdx.x & 15) * 32 + t], v);
  }
}

// ------------- prediction head (1 block, 64 threads) -----------------------
__global__ void pred_kernel(
    const float* __restrict__ gsum16, const float* __restrict__ hW1,
    const float* __restrict__ hb1, const float* __restrict__ hW2,
    const float* __restrict__ hb2, float* __restrict__ out, int N) {
  int j = threadIdx.x;
  float invN = 1.0f / (float)N;
  float acc = hb1[j];
  #pragma unroll
  for (int c = 0; c < 32; ++c) {
    float gv = 0.f;
    #pragma unroll
    for (int r = 0; r < 16; ++r) gv += gsum16[r * 32 + c];
    acc += (gv * invN) * hW1[c * 64 + j];
  }
  acc = fmaxf(acc, 0.f);
  float v = acc * hW2[j];
  #pragma unroll
  for (int off = 1; off < 64; off <<= 1) v += __shfl_xor(v, off);
  if (j == 0) out[(size_t)N * 32] = v + hb2[0];
}

// ---------------------------------------------------------------------------
extern "C" void kernel_launch(void* const* d_in, const int* in_sizes, int n_in,
                              void* d_out, int out_size, void* d_ws, size_t ws_size,
                              hipStream_t stream) {
  const float* x       = (const float*)d_in[0];
  const int*   ei      = (const int*)d_in[1];
  const float* W0      = (const float*)d_in[2];
  const float* a_src0  = (const float*)d_in[3];
  const float* a_dst0  = (const float*)d_in[4];
  const float* b0      = (const float*)d_in[5];
  const float* bn_g    = (const float*)d_in[6];
  const float* bn_b    = (const float*)d_in[7];
  const float* bn_m    = (const float*)d_in[8];
  const float* bn_v    = (const float*)d_in[9];
  const float* W1      = (const float*)d_in[10];
  const float* a_src1  = (const float*)d_in[11];
  const float* a_dst1  = (const float*)d_in[12];
  const float* b1      = (const float*)d_in[13];
  const float* hW1     = (const float*)d_in[14];
  const float* hb1     = (const float*)d_in[15];
  const float* hW2     = (const float*)d_in[16];
  const float* hb2     = (const float*)d_in[17];

  const int N = in_sizes[0] / 128;
  const int E = in_sizes[1] / 2;
  const int Etot = E + N;
  const int* srcs = ei;
  const int* dsts = ei + E;
  const int NB = (N + 255) / 256;

  float* out = (float*)d_out;

  // workspace layout (4-byte units)
  float* ws = (float*)d_ws;
  size_t off = 0;
  unsigned short* h0bf   = (unsigned short*)(ws + off); off += (size_t)N * 128;
  unsigned short* h1bf   = (unsigned short*)(ws + off); off += (size_t)N * 16;
  unsigned short* w0sw   = (unsigned short*)(ws + off); off += 16384;
  unsigned short* w1sw   = (unsigned short*)(ws + off); off += 4096;
  float* as0    = ws + off; off += (size_t)N * 4;
  float* ad0    = ws + off; off += (size_t)N * 4;
  float* as1    = ws + off; off += (size_t)N;
  float* ad1    = ws + off; off += (size_t)N;
  int* rowptr   = (int*)(ws + off); off += (size_t)N + 1;
  int* cursor   = (int*)(ws + off); off += (size_t)N;
  int* bsum     = (int*)(ws + off); off += 256;
  int* csr_src  = (int*)(ws + off); off += (size_t)Etot;
  // --- zeroed region (contiguous): deg + gsum replicas ---
  size_t zoff = off;
  int* deg      = (int*)(ws + off); off += (size_t)N;
  float* gsum16 = ws + off; off += 512;

  hipMemsetAsync(ws + zoff, 0, (off - zoff) * sizeof(float), stream);

  auto cdiv = [](long a, long b) { return (int)((a + b - 1) / b); };

  // CSR histogram + merged weight swizzle
  const int histBlocks = cdiv(Etot, 256);
  hist_swz_kernel<<<histBlocks + 160, 256, 0, stream>>>(
      dsts, deg, E, N, histBlocks, W0, W1, w0sw, w1sw);
  scan_block_kernel<<<NB, 256, 0, stream>>>(deg, rowptr, bsum, N);
  scan_add_kernel<<<NB, 256, 0, stream>>>(rowptr, bsum, cursor, N, Etot);
  scatter_kernel<<<cdiv(Etot, 256), 256, 0, stream>>>(srcs, dsts, cursor, csr_src, E, N);

  // layer 0
  gemm0_mfma_kernel<<<cdiv(N, 64), 256, 0, stream>>>(
      x, w0sw, a_src0, a_dst0, h0bf, as0, ad0, N);
  // layer-0 aggregate + per-wave fused GEMM1 (barrier-free)
  agg0_kernel<<<cdiv(N, 4), 256, 0, stream>>>(
      rowptr, csr_src, h0bf, as0, ad0, b0, bn_g, bn_b, bn_m, bn_v,
      w1sw, a_src1, a_dst1, h1bf, as1, ad1, N);

  // layer-1 aggregate + relaxed gsum accumulation
  agg1_kernel<<<cdiv(N, 4), 256, 0, stream>>>(rowptr, csr_src, h1bf, as1, ad1,
                                              b1, out, gsum16, N);

  // prediction head (ordering via kernel boundary)
  pred_kernel<<<1, 64, 0, stream>>>(gsum16, hW1, hb1, hW2, hb2, out, N);
}

// Round 10
// 233.470 us; speedup vs baseline: 1.0626x; 1.0626x over previous
//
#include <hip/hip_runtime.h>

// ---------------------------------------------------------------------------
// SupervisedGATEncoder: 2-layer GAT (4 heads x 64 -> BN -> ReLU -> 1 head x 32)
// + graph-mean prediction head.
//
// R16: R14 structure (best: 236.7 us) with ONE change — agg0 per-group body
// reordered: batch-0's 8 row gathers issue FIRST, then next-group csr_src
// prefetch, then the as0-weight chain (gather+exp2+slab) runs WHILE the 8
// row loads are in flight, then consume. Same 8-wide live set as R14 (VGPR
// ~40, unlike R12's 16-wide burst that cost occupancy). R15's per-wave MFMA
// tail reverted (dependent-chain tail per wave regressed 68->84 us).
// Rest as R14: merged hist+swizzle, per-block fused gemm1 tail, agg1 dedup
// + relaxed-atomic gsum, 1-block pred, exp2/log2e folding, merged scans.
// ---------------------------------------------------------------------------

#define NEG_SLOPE 0.2f
#define BN_EPS 1e-5f
#define LOG2E 1.4426950408889634f

typedef __attribute__((ext_vector_type(8))) short bf16x8;
typedef __attribute__((ext_vector_type(4))) float f32x4;

__device__ __forceinline__ float bf2f(unsigned short u) {
  return __uint_as_float((unsigned)u << 16);
}
__device__ __forceinline__ unsigned short f2bf(float f) {
  unsigned u = __float_as_uint(f);
  u += 0x7fff + ((u >> 16) & 1);   // round-to-nearest-even
  return (unsigned short)(u >> 16);
}

// -------- CSR histogram + (merged) W0/W1 bf16 swizzle ----------------------
__global__ __launch_bounds__(256) void hist_swz_kernel(
    const int* __restrict__ dsts, int* __restrict__ deg, int E, int N,
    int histBlocks, const float* __restrict__ W0, const float* __restrict__ W1,
    unsigned short* __restrict__ w0sw, unsigned short* __restrict__ w1sw) {
  const int b = blockIdx.x;
  if (b < histBlocks) {
    int e = b * 256 + threadIdx.x;
    if (e >= E + N) return;
    int d = (e < E) ? dsts[e] : e - E;
    atomicAdd(&deg[d], 1);
  } else {
    int o = (b - histBlocks) * 256 + threadIdx.x;
    if (o < 32768) {
      int j = o & 7, l = (o >> 3) & 63, ks = (o >> 9) & 3,
          ci = (o >> 11) & 3, h = (o >> 13) & 3;
      int row = ks * 32 + (l >> 4) * 8 + j;
      int col = h * 64 + ci * 16 + (l & 15);
      w0sw[o] = f2bf(W0[row * 256 + col]);
    } else if (o < 40960) {
      int o2 = o - 32768;
      int j = o2 & 7, l = (o2 >> 3) & 63, ks = (o2 >> 9) & 7, ci = (o2 >> 12) & 1;
      int row = ks * 32 + (l >> 4) * 8 + j;
      int col = ci * 16 + (l & 15);
      w1sw[o2] = f2bf(W1[row * 32 + col]);
    }
  }
}

// ---------------- GEMM0 (MFMA): h0[M,256] = x[M,128] @ W0[128,256] ---------
__global__ __launch_bounds__(256) void gemm0_mfma_kernel(
    const float* __restrict__ x, const unsigned short* __restrict__ w0sw,
    const float* __restrict__ a_src0, const float* __restrict__ a_dst0,
    unsigned short* __restrict__ h0bf, float* __restrict__ as0,
    float* __restrict__ ad0, int M) {
  __shared__ unsigned short Asw[16 * 64 * 8];   // 16 KB
  const int t = threadIdx.x;
  const int lane = t & 63;
  const int h = t >> 6;            // wave id == head
  const int row0 = blockIdx.x * 64;

  #pragma unroll
  for (int i = 0; i < 8; ++i) {
    int q = t + 256 * i;
    int r = q >> 5, c4 = q & 31;
    int gr = row0 + r;
    float4 v = make_float4(0.f, 0.f, 0.f, 0.f);
    if (gr < M) v = *reinterpret_cast<const float4*>(&x[(size_t)gr * 128 + c4 * 4]);
    int ks = c4 >> 3;
    int lane_hi = (c4 >> 1) & 3;
    int j0 = (c4 & 1) * 4;
    int slot = (r >> 4) * 4 + ks;
    int dlane = (r & 15) + 16 * lane_hi;
    ushort4 o;
    o.x = f2bf(v.x); o.y = f2bf(v.y); o.z = f2bf(v.z); o.w = f2bf(v.w);
    *reinterpret_cast<ushort4*>(&Asw[(slot * 64 + dlane) * 8 + j0]) = o;
  }
  __syncthreads();

  f32x4 acc[4][4] = {};
  const bf16x8* wp = reinterpret_cast<const bf16x8*>(w0sw);
  #pragma unroll
  for (int ks = 0; ks < 4; ++ks) {
    bf16x8 bfrag[4];
    #pragma unroll
    for (int ci = 0; ci < 4; ++ci)
      bfrag[ci] = wp[(h * 16 + ci * 4 + ks) * 64 + lane];
    #pragma unroll
    for (int ri = 0; ri < 4; ++ri) {
      bf16x8 af = *reinterpret_cast<const bf16x8*>(&Asw[((ri * 4 + ks) * 64 + lane) * 8]);
      #pragma unroll
      for (int ci = 0; ci < 4; ++ci)
        acc[ri][ci] = __builtin_amdgcn_mfma_f32_16x16x32_bf16(af, bfrag[ci], acc[ri][ci], 0, 0, 0);
    }
  }

  float av[4], dv[4];
  #pragma unroll
  for (int ci = 0; ci < 4; ++ci) {
    av[ci] = a_src0[h * 64 + ci * 16 + (lane & 15)];
    dv[ci] = a_dst0[h * 64 + ci * 16 + (lane & 15)];
  }
  const int mrow = (lane >> 4) * 4;
  #pragma unroll
  for (int ri = 0; ri < 4; ++ri) {
    #pragma unroll
    for (int r = 0; r < 4; ++r) {
      int gr = row0 + ri * 16 + mrow + r;
      float ps = acc[ri][0][r] * av[0] + acc[ri][1][r] * av[1] +
                 acc[ri][2][r] * av[2] + acc[ri][3][r] * av[3];
      float pd = acc[ri][0][r] * dv[0] + acc[ri][1][r] * dv[1] +
                 acc[ri][2][r] * dv[2] + acc[ri][3][r] * dv[3];
      #pragma unroll
      for (int off = 1; off < 16; off <<= 1) {
        ps += __shfl_xor(ps, off);
        pd += __shfl_xor(pd, off);
      }
      if (gr < M) {
        #pragma unroll
        for (int ci = 0; ci < 4; ++ci)
          h0bf[(size_t)gr * 256 + h * 64 + ci * 16 + (lane & 15)] = f2bf(acc[ri][ci][r]);
        // pre-scale by log2(e): consumer uses exp2(max(x, .2x))
        if ((lane & 15) == 0) { as0[gr * 4 + h] = ps * LOG2E; ad0[gr * 4 + h] = pd * LOG2E; }
      }
    }
  }
}

// ------------------------- CSR scans + scatter -----------------------------
__global__ __launch_bounds__(256) void scan_block_kernel(
    const int* __restrict__ deg, int* __restrict__ excl,
    int* __restrict__ bsum, int N) {
  __shared__ int tmp[256];
  int i = blockIdx.x * 256 + threadIdx.x;
  int v = (i < N) ? deg[i] : 0;
  tmp[threadIdx.x] = v;
  __syncthreads();
  #pragma unroll
  for (int off = 1; off < 256; off <<= 1) {
    int t = (threadIdx.x >= off) ? tmp[threadIdx.x - off] : 0;
    __syncthreads();
    tmp[threadIdx.x] += t;
    __syncthreads();
  }
  if (i < N) excl[i] = tmp[threadIdx.x] - v;
  if (threadIdx.x == 255) bsum[blockIdx.x] = tmp[255];
}

// scan_add computes its own block prefix from bsum (NB <= 256).
__global__ __launch_bounds__(256) void scan_add_kernel(
    int* __restrict__ rowptr, const int* __restrict__ bsum,
    int* __restrict__ cursor, int N, int Etot) {
  __shared__ int wred[4];
  const int t = threadIdx.x;
  int v = (t < blockIdx.x) ? bsum[t] : 0;   // blockIdx.x <= NB-1 <= 255
  #pragma unroll
  for (int off = 32; off >= 1; off >>= 1) v += __shfl_xor(v, off);
  if ((t & 63) == 0) wred[t >> 6] = v;
  __syncthreads();
  const int prefix = wred[0] + wred[1] + wred[2] + wred[3];
  int i = blockIdx.x * 256 + t;
  if (i < N) {
    int r = rowptr[i] + prefix;
    rowptr[i] = r;
    cursor[i] = r;
  }
  if (i == 0) rowptr[N] = Etot;
}

__global__ __launch_bounds__(256) void scatter_kernel(
    const int* __restrict__ srcs, const int* __restrict__ dsts,
    int* __restrict__ cursor, int* __restrict__ csr_src, int E, int N) {
  int e = blockIdx.x * 256 + threadIdx.x;
  if (e >= E + N) return;
  int s, d;
  if (e < E) { s = srcs[e]; d = dsts[e]; } else { s = d = e - E; }
  int pos = atomicAdd(&cursor[d], 1);
  csr_src[pos] = s;
}

// ------ layer-0 aggregate (overlap-ordered) + FUSED gemm1 ------------------
// One wave per node. Per 16-edge group: issue batch-0's 8 row gathers FIRST,
// then prefetch next group's csr_src, then the as0 weight chain (gather +
// exp2 + slab) overlapping the in-flight loads, then consume batch 0; batch
// 1 (slots 8-15) as before. Clamped srcs + zero-padded weights = exact.
// Epilogue: BN+ReLU tile staged bf16 into LDS in MFMA-A order; wave 0
// computes h1[4,32] = tile @ W1 + as1/ad1.
__global__ __launch_bounds__(256) void agg0_kernel(
    const int* __restrict__ rowptr, const int* __restrict__ csr_src,
    const unsigned short* __restrict__ h0bf, const float* __restrict__ as0,
    const float* __restrict__ ad0, const float* __restrict__ b0,
    const float* __restrict__ gamma, const float* __restrict__ beta,
    const float* __restrict__ mean, const float* __restrict__ var,
    const unsigned short* __restrict__ w1sw,
    const float* __restrict__ a_src1, const float* __restrict__ a_dst1,
    unsigned short* __restrict__ h1bf, float* __restrict__ as1,
    float* __restrict__ ad1, int N) {
  __shared__ float wlds[4][64];                // wave-private weight slab
  __shared__ unsigned short Asw2[8 * 64 * 8];  // 8 KB A-tile, swizzled
  const int lane = threadIdx.x & 63;
  const int wid = threadIdx.x >> 6;
  const int n = blockIdx.x * 4 + wid;
  const bool valid = n < N;                    // wave-uniform
  const int h = lane >> 4;
  const int eidx = lane & 15;
  const int bb = lane & 48;

  if (valid) {
    const int beg = rowptr[n], end = rowptr[n + 1];
    const float adv = ad0[n * 4 + h];
    float4 acc = make_float4(0.f, 0.f, 0.f, 0.f);
    float wsum = 0.f;

    int i = beg;
    int ne = (end - i < 16) ? (end - i) : 16;
    int src = csr_src[i + (eidx < ne ? eidx : ne - 1)];

    #pragma unroll 1
    while (i < end) {
      const int srccur = src;
      const int necur = ne;

      // ---- issue batch-0's 8 row gathers FIRST (srcs already resident) ----
      const int s0 = __builtin_amdgcn_readlane(srccur, 0);
      const int s1 = __builtin_amdgcn_readlane(srccur, 1);
      const int s2 = __builtin_amdgcn_readlane(srccur, 2);
      const int s3 = __builtin_amdgcn_readlane(srccur, 3);
      const int s4 = __builtin_amdgcn_readlane(srccur, 4);
      const int s5 = __builtin_amdgcn_readlane(srccur, 5);
      const int s6 = __builtin_amdgcn_readlane(srccur, 6);
      const int s7 = __builtin_amdgcn_readlane(srccur, 7);
      ushort4 v0 = *reinterpret_cast<const ushort4*>(&(h0bf + (size_t)s0 * 256)[lane * 4]);
      ushort4 v1 = *reinterpret_cast<const ushort4*>(&(h0bf + (size_t)s1 * 256)[lane * 4]);
      ushort4 v2 = *reinterpret_cast<const ushort4*>(&(h0bf + (size_t)s2 * 256)[lane * 4]);
      ushort4 v3 = *reinterpret_cast<const ushort4*>(&(h0bf + (size_t)s3 * 256)[lane * 4]);
      ushort4 v4 = *reinterpret_cast<const ushort4*>(&(h0bf + (size_t)s4 * 256)[lane * 4]);
      ushort4 v5 = *reinterpret_cast<const ushort4*>(&(h0bf + (size_t)s5 * 256)[lane * 4]);
      ushort4 v6 = *reinterpret_cast<const ushort4*>(&(h0bf + (size_t)s6 * 256)[lane * 4]);
      ushort4 v7 = *reinterpret_cast<const ushort4*>(&(h0bf + (size_t)s7 * 256)[lane * 4]);

      // ---- prefetch next group's src ids (overlaps row loads) ----
      i += 16;
      if (i < end) {
        ne = (end - i < 16) ? (end - i) : 16;
        src = csr_src[i + (eidx < ne ? eidx : ne - 1)];
      }

      // ---- weight chain for current group (overlaps row loads) ----
      float xx = as0[(unsigned)(srccur * 4 + h)] + adv;
      xx = fmaxf(xx, NEG_SLOPE * xx);
      float wl = (eidx < necur) ? exp2f(xx) : 0.f;
      wsum += wl;
      wlds[wid][lane] = wl;                    // same-wave write->read

      // ---- consume batch 0 ----
      {
        const float w0 = wlds[wid][bb + 0], w1 = wlds[wid][bb + 1];
        const float w2 = wlds[wid][bb + 2], w3 = wlds[wid][bb + 3];
        const float w4 = wlds[wid][bb + 4], w5 = wlds[wid][bb + 5];
        const float w6 = wlds[wid][bb + 6], w7 = wlds[wid][bb + 7];
        acc.x += ((w0 * bf2f(v0.x) + w1 * bf2f(v1.x)) + (w2 * bf2f(v2.x) + w3 * bf2f(v3.x))) +
                 ((w4 * bf2f(v4.x) + w5 * bf2f(v5.x)) + (w6 * bf2f(v6.x) + w7 * bf2f(v7.x)));
        acc.y += ((w0 * bf2f(v0.y) + w1 * bf2f(v1.y)) + (w2 * bf2f(v2.y) + w3 * bf2f(v3.y))) +
                 ((w4 * bf2f(v4.y) + w5 * bf2f(v5.y)) + (w6 * bf2f(v6.y) + w7 * bf2f(v7.y)));
        acc.z += ((w0 * bf2f(v0.z) + w1 * bf2f(v1.z)) + (w2 * bf2f(v2.z) + w3 * bf2f(v3.z))) +
                 ((w4 * bf2f(v4.z) + w5 * bf2f(v5.z)) + (w6 * bf2f(v6.z) + w7 * bf2f(v7.z)));
        acc.w += ((w0 * bf2f(v0.w) + w1 * bf2f(v1.w)) + (w2 * bf2f(v2.w) + w3 * bf2f(v3.w))) +
                 ((w4 * bf2f(v4.w) + w5 * bf2f(v5.w)) + (w6 * bf2f(v6.w) + w7 * bf2f(v7.w)));
      }
      // ---- batch 1: slots 8..15 (wave-uniform skip when ne <= 8) ----
      if (necur > 8) {
        const int t0 = __builtin_amdgcn_readlane(srccur, 8);
        const int t1 = __builtin_amdgcn_readlane(srccur, 9);
        const int t2 = __builtin_amdgcn_readlane(srccur, 10);
        const int t3 = __builtin_amdgcn_readlane(srccur, 11);
        const int t4 = __builtin_amdgcn_readlane(srccur, 12);
        const int t5 = __builtin_amdgcn_readlane(srccur, 13);
        const int t6 = __builtin_amdgcn_readlane(srccur, 14);
        const int t7 = __builtin_amdgcn_readlane(srccur, 15);
        ushort4 u0 = *reinterpret_cast<const ushort4*>(&(h0bf + (size_t)t0 * 256)[lane * 4]);
        ushort4 u1 = *reinterpret_cast<const ushort4*>(&(h0bf + (size_t)t1 * 256)[lane * 4]);
        ushort4 u2 = *reinterpret_cast<const ushort4*>(&(h0bf + (size_t)t2 * 256)[lane * 4]);
        ushort4 u3 = *reinterpret_cast<const ushort4*>(&(h0bf + (size_t)t3 * 256)[lane * 4]);
        ushort4 u4 = *reinterpret_cast<const ushort4*>(&(h0bf + (size_t)t4 * 256)[lane * 4]);
        ushort4 u5 = *reinterpret_cast<const ushort4*>(&(h0bf + (size_t)t5 * 256)[lane * 4]);
        ushort4 u6 = *reinterpret_cast<const ushort4*>(&(h0bf + (size_t)t6 * 256)[lane * 4]);
        ushort4 u7 = *reinterpret_cast<const ushort4*>(&(h0bf + (size_t)t7 * 256)[lane * 4]);
        const float w0 = wlds[wid][bb + 8],  w1 = wlds[wid][bb + 9];
        const float w2 = wlds[wid][bb + 10], w3 = wlds[wid][bb + 11];
        const float w4 = wlds[wid][bb + 12], w5 = wlds[wid][bb + 13];
        const float w6 = wlds[wid][bb + 14], w7 = wlds[wid][bb + 15];
        acc.x += ((w0 * bf2f(u0.x) + w1 * bf2f(u1.x)) + (w2 * bf2f(u2.x) + w3 * bf2f(u3.x))) +
                 ((w4 * bf2f(u4.x) + w5 * bf2f(u5.x)) + (w6 * bf2f(u6.x) + w7 * bf2f(u7.x)));
        acc.y += ((w0 * bf2f(u0.y) + w1 * bf2f(u1.y)) + (w2 * bf2f(u2.y) + w3 * bf2f(u3.y))) +
                 ((w4 * bf2f(u4.y) + w5 * bf2f(u5.y)) + (w6 * bf2f(u6.y) + w7 * bf2f(u7.y)));
        acc.z += ((w0 * bf2f(u0.z) + w1 * bf2f(u1.z)) + (w2 * bf2f(u2.z) + w3 * bf2f(u3.z))) +
                 ((w4 * bf2f(u4.z) + w5 * bf2f(u5.z)) + (w6 * bf2f(u6.z) + w7 * bf2f(u7.z)));
        acc.w += ((w0 * bf2f(u0.w) + w1 * bf2f(u1.w)) + (w2 * bf2f(u2.w) + w3 * bf2f(u3.w))) +
                 ((w4 * bf2f(u4.w) + w5 * bf2f(u5.w)) + (w6 * bf2f(u6.w) + w7 * bf2f(u7.w)));
      }
    }

    // reduce wsum across the 16 lanes of this head group
    #pragma unroll
    for (int off = 1; off < 16; off <<= 1) wsum += __shfl_xor(wsum, off);

    const float inv = 1.0f / wsum;
    const int j = lane * 4;
    float4 bbv = *reinterpret_cast<const float4*>(&b0[j]);
    float4 mu = *reinterpret_cast<const float4*>(&mean[j]);
    float4 gg = *reinterpret_cast<const float4*>(&gamma[j]);
    float4 vv = *reinterpret_cast<const float4*>(&var[j]);
    float4 be = *reinterpret_cast<const float4*>(&beta[j]);
    float4 o;
    o.x = (acc.x * inv + bbv.x - mu.x) * (gg.x * rsqrtf(vv.x + BN_EPS)) + be.x;
    o.y = (acc.y * inv + bbv.y - mu.y) * (gg.y * rsqrtf(vv.y + BN_EPS)) + be.y;
    o.z = (acc.z * inv + bbv.z - mu.z) * (gg.z * rsqrtf(vv.z + BN_EPS)) + be.z;
    o.w = (acc.w * inv + bbv.w - mu.w) * (gg.w * rsqrtf(vv.w + BN_EPS)) + be.w;
    ushort4 ob;
    ob.x = f2bf(fmaxf(o.x, 0.f)); ob.y = f2bf(fmaxf(o.y, 0.f));
    ob.z = f2bf(fmaxf(o.z, 0.f)); ob.w = f2bf(fmaxf(o.w, 0.f));
    // stage into LDS in MFMA-A-fragment order: row=wid, cols 4*lane..4*lane+3
    const int ks = lane >> 3;
    const int lane_hi = (lane >> 1) & 3;
    const int j0 = (lane & 1) * 4;
    const int dlane = wid + 16 * lane_hi;
    *reinterpret_cast<ushort4*>(&Asw2[(ks * 64 + dlane) * 8 + j0]) = ob;
  }
  __syncthreads();

  // ---- fused GEMM1 tail: wave 0 computes h1[4,32] = tile(4x256) @ W1 ----
  if (wid == 0) {
    const bf16x8* bp = reinterpret_cast<const bf16x8*>(w1sw);
    f32x4 c0 = {}, c1 = {};
    #pragma unroll
    for (int ks = 0; ks < 8; ++ks) {
      bf16x8 af = *reinterpret_cast<const bf16x8*>(&Asw2[(ks * 64 + lane) * 8]);
      c0 = __builtin_amdgcn_mfma_f32_16x16x32_bf16(af, bp[(0 * 8 + ks) * 64 + lane], c0, 0, 0, 0);
      c1 = __builtin_amdgcn_mfma_f32_16x16x32_bf16(af, bp[(1 * 8 + ks) * 64 + lane], c1, 0, 0, 0);
    }
    const float av0 = a_src1[lane & 15], av1 = a_src1[16 + (lane & 15)];
    const float dv0 = a_dst1[lane & 15], dv1 = a_dst1[16 + (lane & 15)];
    const int rowgrp = lane >> 4;            // only rowgrp==0 holds rows 0-3
    #pragma unroll
    for (int r = 0; r < 4; ++r) {
      float ps = c0[r] * av0 + c1[r] * av1;
      float pd = c0[r] * dv0 + c1[r] * dv1;
      #pragma unroll
      for (int off = 1; off < 16; off <<= 1) {
        ps += __shfl_xor(ps, off);
        pd += __shfl_xor(pd, off);
      }
      const int gn = blockIdx.x * 4 + r;
      if (rowgrp == 0 && gn < N) {
        h1bf[(size_t)gn * 32 + (lane & 15)]      = f2bf(c0[r]);
        h1bf[(size_t)gn * 32 + 16 + (lane & 15)] = f2bf(c1[r]);
        if ((lane & 15) == 0) { as1[gn] = ps * LOG2E; ad1[gn] = pd * LOG2E; }
      }
    }
  }
}

// ------ layer-1 aggregate (dedup weights) + relaxed gsum accumulation ------
// Per-block: 4 nodes; after writing out rows, block reduces them into a
// 32-col partial and atomicAdds into one of 16 gsum replicas. No fence,
// no ticket: the following 1-block pred kernel provides ordering.
__global__ __launch_bounds__(256) void agg1_kernel(
    const int* __restrict__ rowptr, const int* __restrict__ csr_src,
    const unsigned short* __restrict__ h1bf, const float* __restrict__ as1,
    const float* __restrict__ ad1, const float* __restrict__ b1,
    float* __restrict__ out, float* __restrict__ gsum16, int N) {
  __shared__ float wslab[4][16];
  __shared__ int sslab[4][16];
  __shared__ float gred[4][32];
  const int t = threadIdx.x;
  const int lane = t & 63;
  const int wid = t >> 6;
  const int n = blockIdx.x * 4 + wid;
  const bool valid = n < N;
  const int c = lane & 31;
  const int half = lane >> 5;
  float val = 0.f;

  if (valid) {
    const int beg = rowptr[n], end = rowptr[n + 1];
    const float adv = ad1[n];
    float acc = 0.f, wsum = 0.f;

    for (int i = beg; i < end; i += 16) {
      int ne = end - i; if (ne > 16) ne = 16;
      if (lane < 16) {
        const int idx = lane < ne ? lane : ne - 1;
        const int s = csr_src[i + idx];
        const float x = as1[s] + adv;
        const float wl = (lane < ne) ? exp2f(fmaxf(x, NEG_SLOPE * x)) : 0.f;
        wslab[wid][lane] = wl;
        sslab[wid][lane] = s;
        wsum += wl;
      }
      for (int e = 0; e < ne; e += 8) {
        const int i0 = e + half, i1 = e + 2 + half, i2 = e + 4 + half, i3 = e + 6 + half;
        const int s0 = sslab[wid][i0], s1 = sslab[wid][i1],
                  s2 = sslab[wid][i2], s3 = sslab[wid][i3];
        const float w0 = wslab[wid][i0], w1 = wslab[wid][i1],
                    w2 = wslab[wid][i2], w3 = wslab[wid][i3];
        const unsigned short u0 = h1bf[(size_t)s0 * 32 + c];
        const unsigned short u1 = h1bf[(size_t)s1 * 32 + c];
        const unsigned short u2 = h1bf[(size_t)s2 * 32 + c];
        const unsigned short u3 = h1bf[(size_t)s3 * 32 + c];
        acc += (w0 * bf2f(u0) + w1 * bf2f(u1)) + (w2 * bf2f(u2) + w3 * bf2f(u3));
      }
    }
    // lanes 0-15 hold wsum partials; reduce within 16-group, then broadcast
    #pragma unroll
    for (int off = 1; off < 16; off <<= 1) wsum += __shfl_xor(wsum, off);
    wsum = __shfl(wsum, lane & 15);
    acc += __shfl_xor(acc, 32);
    if (half == 0) {
      val = acc / wsum + b1[c];
      out[(size_t)n * 32 + c] = val;
    }
  }

  // ---- block-level graph-sum partial (relaxed atomics, no fence) ----
  if (half == 0) gred[wid][c] = val;   // val==0 for invalid nodes
  __syncthreads();
  if (t < 32) {
    float v = gred[0][t] + gred[1][t] + gred[2][t] + gred[3][t];
    atomicAdd(&gsum16[(blockIdx.x & 15) * 32 + t], v);
  }
}

// ------------- prediction head (1 block, 64 threads) -----------------------
__global__ void pred_kernel(
    const float* __restrict__ gsum16, const float* __restrict__ hW1,
    const float* __restrict__ hb1, const float* __restrict__ hW2,
    const float* __restrict__ hb2, float* __restrict__ out, int N) {
  int j = threadIdx.x;
  float invN = 1.0f / (float)N;
  float acc = hb1[j];
  #pragma unroll
  for (int c = 0; c < 32; ++c) {
    float gv = 0.f;
    #pragma unroll
    for (int r = 0; r < 16; ++r) gv += gsum16[r * 32 + c];
    acc += (gv * invN) * hW1[c * 64 + j];
  }
  acc = fmaxf(acc, 0.f);
  float v = acc * hW2[j];
  #pragma unroll
  for (int off = 1; off < 64; off <<= 1) v += __shfl_xor(v, off);
  if (j == 0) out[(size_t)N * 32] = v + hb2[0];
}

// ---------------------------------------------------------------------------
extern "C" void kernel_launch(void* const* d_in, const int* in_sizes, int n_in,
                              void* d_out, int out_size, void* d_ws, size_t ws_size,
                              hipStream_t stream) {
  const float* x       = (const float*)d_in[0];
  const int*   ei      = (const int*)d_in[1];
  const float* W0      = (const float*)d_in[2];
  const float* a_src0  = (const float*)d_in[3];
  const float* a_dst0  = (const float*)d_in[4];
  const float* b0      = (const float*)d_in[5];
  const float* bn_g    = (const float*)d_in[6];
  const float* bn_b    = (const float*)d_in[7];
  const float* bn_m    = (const float*)d_in[8];
  const float* bn_v    = (const float*)d_in[9];
  const float* W1      = (const float*)d_in[10];
  const float* a_src1  = (const float*)d_in[11];
  const float* a_dst1  = (const float*)d_in[12];
  const float* b1      = (const float*)d_in[13];
  const float* hW1     = (const float*)d_in[14];
  const float* hb1     = (const float*)d_in[15];
  const float* hW2     = (const float*)d_in[16];
  const float* hb2     = (const float*)d_in[17];

  const int N = in_sizes[0] / 128;
  const int E = in_sizes[1] / 2;
  const int Etot = E + N;
  const int* srcs = ei;
  const int* dsts = ei + E;
  const int NB = (N + 255) / 256;

  float* out = (float*)d_out;

  // workspace layout (4-byte units)
  float* ws = (float*)d_ws;
  size_t off = 0;
  unsigned short* h0bf   = (unsigned short*)(ws + off); off += (size_t)N * 128;
  unsigned short* h1bf   = (unsigned short*)(ws + off); off += (size_t)N * 16;
  unsigned short* w0sw   = (unsigned short*)(ws + off); off += 16384;
  unsigned short* w1sw   = (unsigned short*)(ws + off); off += 4096;
  float* as0    = ws + off; off += (size_t)N * 4;
  float* ad0    = ws + off; off += (size_t)N * 4;
  float* as1    = ws + off; off += (size_t)N;
  float* ad1    = ws + off; off += (size_t)N;
  int* rowptr   = (int*)(ws + off); off += (size_t)N + 1;
  int* cursor   = (int*)(ws + off); off += (size_t)N;
  int* bsum     = (int*)(ws + off); off += 256;
  int* csr_src  = (int*)(ws + off); off += (size_t)Etot;
  // --- zeroed region (contiguous): deg + gsum replicas ---
  size_t zoff = off;
  int* deg      = (int*)(ws + off); off += (size_t)N;
  float* gsum16 = ws + off; off += 512;

  hipMemsetAsync(ws + zoff, 0, (off - zoff) * sizeof(float), stream);

  auto cdiv = [](long a, long b) { return (int)((a + b - 1) / b); };

  // CSR histogram + merged weight swizzle
  const int histBlocks = cdiv(Etot, 256);
  hist_swz_kernel<<<histBlocks + 160, 256, 0, stream>>>(
      dsts, deg, E, N, histBlocks, W0, W1, w0sw, w1sw);
  scan_block_kernel<<<NB, 256, 0, stream>>>(deg, rowptr, bsum, N);
  scan_add_kernel<<<NB, 256, 0, stream>>>(rowptr, bsum, cursor, N, Etot);
  scatter_kernel<<<cdiv(Etot, 256), 256, 0, stream>>>(srcs, dsts, cursor, csr_src, E, N);

  // layer 0
  gemm0_mfma_kernel<<<cdiv(N, 64), 256, 0, stream>>>(
      x, w0sw, a_src0, a_dst0, h0bf, as0, ad0, N);
  // layer-0 aggregate + fused GEMM1
  agg0_kernel<<<cdiv(N, 4), 256, 0, stream>>>(
      rowptr, csr_src, h0bf, as0, ad0, b0, bn_g, bn_b, bn_m, bn_v,
      w1sw, a_src1, a_dst1, h1bf, as1, ad1, N);

  // layer-1 aggregate + relaxed gsum accumulation
  agg1_kernel<<<cdiv(N, 4), 256, 0, stream>>>(rowptr, csr_src, h1bf, as1, ad1,
                                              b1, out, gsum16, N);

  // prediction head (ordering via kernel boundary)
  pred_kernel<<<1, 64, 0, stream>>>(gsum16, hW1, hb1, hW2, hb2, out, N);
}